// Round 4
// baseline (773.379 us; speedup 1.0000x reference)
//
#include <hip/hip_runtime.h>
#include <hip/hip_bf16.h>

#define KH 4
#define DIM 64
#define EPSV 1e-8f

// ---- monotone float<->uint encoding for atomicMax on signed floats ----
__device__ __forceinline__ unsigned fenc(float f) {
    unsigned u = __float_as_uint(f);
    return (u & 0x80000000u) ? ~u : (u | 0x80000000u);
}
__device__ __forceinline__ float fdec(unsigned u) {
    unsigned b = (u & 0x80000000u) ? (u & 0x7FFFFFFFu) : ~u;
    return __uint_as_float(b);
}

// ---- zero-init workspace region (ws is poisoned 0xAA before every launch) ----
__global__ void k_zero(float* __restrict__ p, size_t n) {
    size_t i = (size_t)blockIdx.x * blockDim.x + threadIdx.x;
    size_t stride = (size_t)gridDim.x * blockDim.x;
    for (; i < n; i += stride) p[i] = 0.0f;
}

// ---- h[k,n,:] = x[n,:] @ W[k] (stored bf16); alpha_dst/src[k,n] = h . a ----
// block = 256 threads = 4 waves; wave k handles head k, lane = output dim o.
__global__ void k_hidden(const float* __restrict__ x,
                         const float* __restrict__ W,
                         const float* __restrict__ a,
                         __hip_bfloat16* __restrict__ h,
                         float* __restrict__ adst,
                         float* __restrict__ asrc, int N) {
    int n = blockIdx.x;
    int t = threadIdx.x;
    int k = t >> 6, o = t & 63;
    __shared__ float xs[DIM];
    if (t < DIM) xs[t] = x[(size_t)n * DIM + t];
    __syncthreads();
    const float* Wk = W + k * DIM * DIM;
    float acc = 0.0f;
#pragma unroll
    for (int d = 0; d < DIM; ++d)
        acc = fmaf(xs[d], Wk[d * DIM + o], acc);
    h[((size_t)k * N + n) * DIM + o] = __float2bfloat16(acc);
    // attention dot products: reduce acc*a over the 64 lanes of this wave
    float pd = acc * a[k * 2 * DIM + o];
    float ps = acc * a[k * 2 * DIM + DIM + o];
#pragma unroll
    for (int off = 32; off; off >>= 1) {
        pd += __shfl_down(pd, off);
        ps += __shfl_down(ps, off);
    }
    if (o == 0) {
        adst[k * N + n] = pd;
        asrc[k * N + n] = ps;
    }
}

// ---- per-head global max over edges of leaky_relu(alpha_dst[dst]+alpha_src[src]) ----
__global__ void k_max(const int* __restrict__ dst, const int* __restrict__ src,
                      const float* __restrict__ adst, const float* __restrict__ asrc,
                      unsigned* __restrict__ gmax, int N, int E) {
    float m[KH] = {-1e30f, -1e30f, -1e30f, -1e30f};
    for (int e = blockIdx.x * blockDim.x + threadIdx.x; e < E;
         e += gridDim.x * blockDim.x) {
        int dn = dst[e], sn = src[e];
#pragma unroll
        for (int k = 0; k < KH; ++k) {
            float s = adst[k * N + dn] + asrc[k * N + sn];
            float l = s > 0.0f ? s : 0.01f * s;
            m[k] = fmaxf(m[k], l);
        }
    }
#pragma unroll
    for (int k = 0; k < KH; ++k) {
        float v = m[k];
#pragma unroll
        for (int off = 32; off; off >>= 1) v = fmaxf(v, __shfl_down(v, off));
        if ((threadIdx.x & 63) == 0) atomicMax(&gmax[k], fenc(v));
    }
}

// ---- denom[k,dst] += exp(lrelu(...) - gmax[k]) : one thread per edge ----
__global__ void k_denom(const int* __restrict__ dst, const int* __restrict__ src,
                        const float* __restrict__ adst, const float* __restrict__ asrc,
                        const unsigned* __restrict__ gmax,
                        float* __restrict__ denomseg, int N, int E) {
    float mk[KH];
#pragma unroll
    for (int k = 0; k < KH; ++k) mk[k] = fdec(gmax[k]);
    int stride = gridDim.x * blockDim.x;
    for (int e = blockIdx.x * blockDim.x + threadIdx.x; e < E; e += stride) {
        int dn = dst[e], sn = src[e];
#pragma unroll
        for (int k = 0; k < KH; ++k) {
            float s = adst[k * N + dn] + asrc[k * N + sn];
            float l = s > 0.0f ? s : 0.01f * s;
            atomicAdd(&denomseg[k * N + dn], __expf(l - mk[k]));
        }
    }
}

// ---- fused scatter: accum[dst,:] += sum_k (e[dst,k]*w_k/(denom_k+eps)) * h[k,src,:] ----
// one wave per edge; lane = output dim. 64 f32 atomics per edge.
__global__ void k_scatter(const int* __restrict__ dst, const int* __restrict__ src,
                          const float* __restrict__ adst, const float* __restrict__ asrc,
                          const float* __restrict__ efeat,
                          const __hip_bfloat16* __restrict__ h,
                          const unsigned* __restrict__ gmax,
                          const float* __restrict__ denomseg,
                          float* __restrict__ accum, int N, int E) {
    int lane = threadIdx.x & 63;
    int wid = (int)((blockIdx.x * blockDim.x + threadIdx.x) >> 6);
    int nw = (int)((gridDim.x * blockDim.x) >> 6);
    float mk[KH];
#pragma unroll
    for (int k = 0; k < KH; ++k) mk[k] = fdec(gmax[k]);
    for (int e = wid; e < E; e += nw) {
        int dn = dst[e], sn = src[e];
        float val = 0.0f;
#pragma unroll
        for (int k = 0; k < KH; ++k) {
            float s = adst[k * N + dn] + asrc[k * N + sn];
            float l = s > 0.0f ? s : 0.01f * s;
            float w = __expf(l - mk[k]);
            float coef = efeat[(size_t)dn * KH + k] * w / (denomseg[k * N + dn] + EPSV);
            val = fmaf(coef, __bfloat162float(h[((size_t)k * N + sn) * DIM + lane]), val);
        }
        atomicAdd(&accum[(size_t)dn * DIM + lane], val);
    }
}

// ---- out[n,:] = f32( x[n,:] + accum[n,:] ) ----
__global__ void k_final(const float* __restrict__ accum,
                        const float* __restrict__ x,
                        float* __restrict__ out, int n_elts) {
    int t = blockIdx.x * blockDim.x + threadIdx.x;
    if (t >= n_elts) return;
    out[t] = x[t] + accum[t];
}

extern "C" void kernel_launch(void* const* d_in, const int* in_sizes, int n_in,
                              void* d_out, int out_size, void* d_ws, size_t ws_size,
                              hipStream_t stream) {
    const float* x = (const float*)d_in[0];
    const int* adj = (const int*)d_in[1];
    const float* efeat = (const float*)d_in[2];
    const float* W = (const float*)d_in[3];
    const float* a = (const float*)d_in[4];
    float* out = (float*)d_out;   // reference output dtype is float32

    int N = in_sizes[0] / DIM;      // 50000
    int E = in_sizes[1] / 2;        // 850000
    const int* dst = adj;
    const int* src = adj + E;

    // workspace layout:
    //   h (bf16, KH*N*DIM) | adst | asrc | denomseg (f32, KH*N each) |
    //   accum (f32, N*DIM) | gmax (u32, KH)    -- total ~41 MB
    __hip_bfloat16* h = (__hip_bfloat16*)d_ws;
    float* adst = (float*)(h + (size_t)KH * N * DIM);
    float* asrc = adst + (size_t)KH * N;
    float* denomseg = asrc + (size_t)KH * N;
    float* accum = denomseg + (size_t)KH * N;
    unsigned* gmax = (unsigned*)(accum + (size_t)N * DIM);

    // zero: denomseg + accum + gmax (contiguous); 0 is the fenc atomicMax identity
    size_t nz = (size_t)KH * N + (size_t)N * DIM + KH;
    k_zero<<<1024, 256, 0, stream>>>(denomseg, nz);

    k_hidden<<<N, 256, 0, stream>>>(x, W, a, h, adst, asrc, N);

    k_max<<<1024, 256, 0, stream>>>(dst, src, adst, asrc, gmax, N, E);

    k_denom<<<1024, 256, 0, stream>>>(dst, src, adst, asrc, gmax, denomseg, N, E);

    k_scatter<<<2048, 256, 0, stream>>>(dst, src, adst, asrc, efeat, h, gmax,
                                        denomseg, accum, N, E);

    int nt = N * DIM;
    k_final<<<(nt + 255) / 256, 256, 0, stream>>>(accum, x, out, nt);
}

// Round 5
// 724.804 us; speedup vs baseline: 1.0670x; 1.0670x over previous
//
#include <hip/hip_runtime.h>
#include <hip/hip_bf16.h>

#define KH 4
#define DIM 64
#define EPSV 1e-8f
#define SCAN_T 1024

// ---- monotone float<->uint encoding for atomicMax on signed floats ----
__device__ __forceinline__ unsigned fenc(float f) {
    unsigned u = __float_as_uint(f);
    return (u & 0x80000000u) ? ~u : (u | 0x80000000u);
}
__device__ __forceinline__ float fdec(unsigned u) {
    unsigned b = (u & 0x80000000u) ? (u & 0x7FFFFFFFu) : ~u;
    return __uint_as_float(b);
}
__device__ __forceinline__ float lrelu(float s) { return s > 0.0f ? s : 0.01f * s; }

// ---- zero-init (ws is poisoned 0xAA before every launch) ----
__global__ void k_zero(int* __restrict__ p, size_t n) {
    size_t i = (size_t)blockIdx.x * blockDim.x + threadIdx.x;
    size_t stride = (size_t)gridDim.x * blockDim.x;
    for (; i < n; i += stride) p[i] = 0;
}

// ---- h[k,n,:] = x[n,:] @ W[k] (stored bf16); alpha[n].k = h . a  (float4/node) ----
__global__ void k_hidden(const float* __restrict__ x,
                         const float* __restrict__ W,
                         const float* __restrict__ a,
                         __hip_bfloat16* __restrict__ h,
                         float* __restrict__ adst4,
                         float* __restrict__ asrc4, int N) {
    int n = blockIdx.x;
    int t = threadIdx.x;
    int k = t >> 6, o = t & 63;
    __shared__ float xs[DIM];
    if (t < DIM) xs[t] = x[(size_t)n * DIM + t];
    __syncthreads();
    const float* Wk = W + k * DIM * DIM;
    float acc = 0.0f;
#pragma unroll
    for (int d = 0; d < DIM; ++d)
        acc = fmaf(xs[d], Wk[d * DIM + o], acc);
    h[((size_t)k * N + n) * DIM + o] = __float2bfloat16(acc);
    float pd = acc * a[k * 2 * DIM + o];
    float ps = acc * a[k * 2 * DIM + DIM + o];
#pragma unroll
    for (int off = 32; off; off >>= 1) {
        pd += __shfl_down(pd, off);
        ps += __shfl_down(ps, off);
    }
    if (o == 0) {
        adst4[n * KH + k] = pd;   // [n][k] layout -> one float4 per node
        asrc4[n * KH + k] = ps;
    }
}

// ---- fused: degree histogram + per-head global max of leaky logits ----
__global__ void k_degmax(const int* __restrict__ dst, const int* __restrict__ src,
                         const float4* __restrict__ adst4, const float4* __restrict__ asrc4,
                         int* __restrict__ deg, unsigned* __restrict__ gmax, int E) {
    float m0 = -1e30f, m1 = -1e30f, m2 = -1e30f, m3 = -1e30f;
    int stride = gridDim.x * blockDim.x;
    for (int e = blockIdx.x * blockDim.x + threadIdx.x; e < E; e += stride) {
        int dn = dst[e], sn = src[e];
        atomicAdd(&deg[dn], 1);
        float4 ad = adst4[dn], as = asrc4[sn];
        m0 = fmaxf(m0, lrelu(ad.x + as.x));
        m1 = fmaxf(m1, lrelu(ad.y + as.y));
        m2 = fmaxf(m2, lrelu(ad.z + as.z));
        m3 = fmaxf(m3, lrelu(ad.w + as.w));
    }
#pragma unroll
    for (int off = 32; off; off >>= 1) {
        m0 = fmaxf(m0, __shfl_down(m0, off));
        m1 = fmaxf(m1, __shfl_down(m1, off));
        m2 = fmaxf(m2, __shfl_down(m2, off));
        m3 = fmaxf(m3, __shfl_down(m3, off));
    }
    if ((threadIdx.x & 63) == 0) {
        atomicMax(&gmax[0], fenc(m0));
        atomicMax(&gmax[1], fenc(m1));
        atomicMax(&gmax[2], fenc(m2));
        atomicMax(&gmax[3], fenc(m3));
    }
}

// ---- single-block exclusive scan: deg -> rowstart, cursor ----
__global__ void k_scan(const int* __restrict__ deg, int* __restrict__ rowstart,
                       int* __restrict__ cursor, int N, int E) {
    __shared__ int ps[SCAN_T];
    int t = threadIdx.x;
    int chunk = (N + SCAN_T - 1) / SCAN_T;
    int lo = t * chunk;
    int hi = lo + chunk; if (hi > N) hi = N; if (lo > N) lo = N;
    int s = 0;
    for (int i = lo; i < hi; ++i) s += deg[i];
    ps[t] = s;
    __syncthreads();
    for (int off = 1; off < SCAN_T; off <<= 1) {
        int v = (t >= off) ? ps[t - off] : 0;
        __syncthreads();
        ps[t] += v;
        __syncthreads();
    }
    int base = (t == 0) ? 0 : ps[t - 1];
    for (int i = lo; i < hi; ++i) {
        rowstart[i] = base;
        cursor[i] = base;
        base += deg[i];
    }
    if (t == SCAN_T - 1) rowstart[N] = E;
}

// ---- counting-sort pass 2 + per-edge weights (dense, full lane utilization) ----
__global__ void k_fill(const int* __restrict__ dst, const int* __restrict__ src,
                       const float4* __restrict__ adst4, const float4* __restrict__ asrc4,
                       const unsigned* __restrict__ gmax,
                       int* __restrict__ cursor, int* __restrict__ csr_src,
                       float4* __restrict__ wq, int E) {
    float mk0 = fdec(gmax[0]), mk1 = fdec(gmax[1]);
    float mk2 = fdec(gmax[2]), mk3 = fdec(gmax[3]);
    int stride = gridDim.x * blockDim.x;
    for (int e = blockIdx.x * blockDim.x + threadIdx.x; e < E; e += stride) {
        int dn = dst[e], sn = src[e];
        int slot = atomicAdd(&cursor[dn], 1);
        csr_src[slot] = sn;
        float4 ad = adst4[dn], as = asrc4[sn];
        float4 w;
        w.x = __expf(lrelu(ad.x + as.x) - mk0);
        w.y = __expf(lrelu(ad.y + as.y) - mk1);
        w.z = __expf(lrelu(ad.z + as.z) - mk2);
        w.w = __expf(lrelu(ad.w + as.w) - mk3);
        wq[slot] = w;
    }
}

// ---- gather-aggregate: one block per dst node, wave k = head k, lane = dim ----
// val_k[o] = sum_e w_e * h[k][src_e][o]; den_k = sum_e w_e  (no atomics)
// out[n][o] = x[n][o] + sum_k e[n,k] * val_k[o] / (den_k + eps)
__global__ void k_aggr(const int* __restrict__ rowstart, const int* __restrict__ csr_src,
                       const float* __restrict__ wq, const __hip_bfloat16* __restrict__ h,
                       const float* __restrict__ efeat, const float* __restrict__ x,
                       float* __restrict__ out, int N) {
    int n = blockIdx.x;
    int t = threadIdx.x, k = t >> 6, o = t & 63;
    int beg = rowstart[n], end = rowstart[n + 1];
    const __hip_bfloat16* hk = h + (size_t)k * N * DIM;
    float val = 0.0f, den = 0.0f;
    for (int i = beg; i < end; ++i) {
        int sn = csr_src[i];
        float w = wq[i * 4 + k];
        den += w;
        val = fmaf(w, __bfloat162float(hk[(size_t)sn * DIM + o]), val);
    }
    float coef = efeat[n * KH + k] / (den + EPSV);
    __shared__ float ls[KH][DIM];
    ls[k][o] = val * coef;
    __syncthreads();
    if (t < DIM)
        out[(size_t)n * DIM + t] = x[(size_t)n * DIM + t] +
                                   ls[0][t] + ls[1][t] + ls[2][t] + ls[3][t];
}

extern "C" void kernel_launch(void* const* d_in, const int* in_sizes, int n_in,
                              void* d_out, int out_size, void* d_ws, size_t ws_size,
                              hipStream_t stream) {
    const float* x = (const float*)d_in[0];
    const int* adj = (const int*)d_in[1];
    const float* efeat = (const float*)d_in[2];
    const float* W = (const float*)d_in[3];
    const float* a = (const float*)d_in[4];
    float* out = (float*)d_out;

    int N = in_sizes[0] / DIM;      // 50000
    int E = in_sizes[1] / 2;        // 850000
    const int* dst = adj;
    const int* src = adj + E;

    // ws layout (16B-aligned chunks first):
    //   h bf16 [KH*N*DIM] | adst4 f32 [N*4] | asrc4 f32 [N*4] | wq f32 [E*4] |
    //   csr_src i32 [E] | deg i32 [N] | gmax u32 [4] | rowstart i32 [N+1] | cursor i32 [N]
    __hip_bfloat16* h = (__hip_bfloat16*)d_ws;
    float* adst4 = (float*)(h + (size_t)KH * N * DIM);
    float* asrc4 = adst4 + (size_t)N * KH;
    float* wq = asrc4 + (size_t)N * KH;
    int* csr_src = (int*)(wq + (size_t)E * 4);
    int* deg = csr_src + E;
    unsigned* gmax = (unsigned*)(deg + N);
    int* rowstart = (int*)(gmax + KH);
    int* cursor = rowstart + (N + 1);

    // zero deg + gmax (contiguous, N+4 ints); 0 is below every fenc() value
    k_zero<<<256, 256, 0, stream>>>(deg, (size_t)N + KH);

    k_hidden<<<N, 256, 0, stream>>>(x, W, a, h, adst4, asrc4, N);

    k_degmax<<<1024, 256, 0, stream>>>(dst, src, (const float4*)adst4,
                                       (const float4*)asrc4, deg, gmax, E);

    k_scan<<<1, SCAN_T, 0, stream>>>(deg, rowstart, cursor, N, E);

    k_fill<<<1024, 256, 0, stream>>>(dst, src, (const float4*)adst4,
                                     (const float4*)asrc4, gmax, cursor,
                                     csr_src, (float4*)wq, E);

    k_aggr<<<N, 256, 0, stream>>>(rowstart, csr_src, wq, h, efeat, x, out, N);
}

// Round 6
// 457.933 us; speedup vs baseline: 1.6888x; 1.5828x over previous
//
#include <hip/hip_runtime.h>
#include <hip/hip_bf16.h>

#define KH 4
#define DIM 64
#define EPSV 1e-8f
#define SCAN_T 1024
#define EDGE_BLKS 2048
#define HID_BLKS 1024

__device__ __forceinline__ float lrelu(float s) { return s > 0.0f ? s : 0.01f * s; }

// ---- zero-init (ws is poisoned 0xAA before every launch) ----
__global__ void k_zero(int* __restrict__ p, size_t n) {
    size_t i = (size_t)blockIdx.x * blockDim.x + threadIdx.x;
    size_t stride = (size_t)gridDim.x * blockDim.x;
    for (; i < n; i += stride) p[i] = 0;
}

// ---- persistent GEMV: h[k,n,:] = x[n,:] @ W[k] (bf16); alpha[n*4+k] = h.a ----
// W column held in 64 VGPRs per thread; block = 4 waves = 4 heads, lane = out dim.
__global__ void k_hidden(const float* __restrict__ x,
                         const float* __restrict__ W,
                         const float* __restrict__ a,
                         __hip_bfloat16* __restrict__ h,
                         float* __restrict__ adst,
                         float* __restrict__ asrc, int N) {
    int t = threadIdx.x;
    int k = t >> 6, o = t & 63;
    const float* Wk = W + k * DIM * DIM;
    float wreg[DIM];
#pragma unroll
    for (int d = 0; d < DIM; ++d) wreg[d] = Wk[d * DIM + o];  // coalesced over o
    float a_d = a[k * 2 * DIM + o];
    float a_s = a[k * 2 * DIM + DIM + o];
    __shared__ float xs[DIM];
    for (int n = blockIdx.x; n < N; n += gridDim.x) {
        __syncthreads();
        if (t < DIM) xs[t] = x[(size_t)n * DIM + t];
        __syncthreads();
        float acc = 0.0f;
#pragma unroll
        for (int d = 0; d < DIM; ++d) acc = fmaf(xs[d], wreg[d], acc);
        h[((size_t)k * N + n) * DIM + o] = __float2bfloat16(acc);
        float pd = acc * a_d, ps = acc * a_s;
#pragma unroll
        for (int off = 32; off; off >>= 1) {
            pd += __shfl_down(pd, off);
            ps += __shfl_down(ps, off);
        }
        if (o == 0) {
            adst[n * KH + k] = pd;
            asrc[n * KH + k] = ps;
        }
    }
}

// ---- pass1: edge rank (deg histogram w/ returned rank) + per-block max partials ----
__global__ void k_pass1(const int* __restrict__ dst, const int* __restrict__ src,
                        const float4* __restrict__ adst4, const float4* __restrict__ asrc4,
                        int* __restrict__ deg, int* __restrict__ erank,
                        float4* __restrict__ pmax, int E) {
    float m0 = -1e30f, m1 = -1e30f, m2 = -1e30f, m3 = -1e30f;
    int stride = gridDim.x * blockDim.x;
    for (int e = blockIdx.x * blockDim.x + threadIdx.x; e < E; e += stride) {
        int dn = dst[e], sn = src[e];
        erank[e] = atomicAdd(&deg[dn], 1);
        float4 ad = adst4[dn], as = asrc4[sn];
        m0 = fmaxf(m0, lrelu(ad.x + as.x));
        m1 = fmaxf(m1, lrelu(ad.y + as.y));
        m2 = fmaxf(m2, lrelu(ad.z + as.z));
        m3 = fmaxf(m3, lrelu(ad.w + as.w));
    }
#pragma unroll
    for (int off = 32; off; off >>= 1) {
        m0 = fmaxf(m0, __shfl_down(m0, off));
        m1 = fmaxf(m1, __shfl_down(m1, off));
        m2 = fmaxf(m2, __shfl_down(m2, off));
        m3 = fmaxf(m3, __shfl_down(m3, off));
    }
    __shared__ float4 red[4];
    int t = threadIdx.x;
    if ((t & 63) == 0) red[t >> 6] = make_float4(m0, m1, m2, m3);
    __syncthreads();
    if (t == 0) {
        float4 r = red[0];
        for (int wv = 1; wv < 4; ++wv) {
            float4 q = red[wv];
            r.x = fmaxf(r.x, q.x); r.y = fmaxf(r.y, q.y);
            r.z = fmaxf(r.z, q.z); r.w = fmaxf(r.w, q.w);
        }
        pmax[blockIdx.x] = r;
    }
}

// ---- scan: pmax -> gmaxf[4]; deg -> rowstart (exclusive) ----
__global__ void k_scan(const float4* __restrict__ pmax, float* __restrict__ gmaxf,
                       const int* __restrict__ deg, int* __restrict__ rowstart,
                       int N, int E) {
    __shared__ float4 s4[SCAN_T];
    __shared__ int ps[SCAN_T];
    int t = threadIdx.x;
    float4 v = pmax[t], v2 = pmax[t + SCAN_T];
    v.x = fmaxf(v.x, v2.x); v.y = fmaxf(v.y, v2.y);
    v.z = fmaxf(v.z, v2.z); v.w = fmaxf(v.w, v2.w);
    s4[t] = v;
    __syncthreads();
    for (int off = SCAN_T / 2; off > 0; off >>= 1) {
        if (t < off) {
            float4 q = s4[t + off];
            s4[t].x = fmaxf(s4[t].x, q.x); s4[t].y = fmaxf(s4[t].y, q.y);
            s4[t].z = fmaxf(s4[t].z, q.z); s4[t].w = fmaxf(s4[t].w, q.w);
        }
        __syncthreads();
    }
    if (t == 0) {
        gmaxf[0] = s4[0].x; gmaxf[1] = s4[0].y;
        gmaxf[2] = s4[0].z; gmaxf[3] = s4[0].w;
    }
    // exclusive scan of deg
    int chunk = (N + SCAN_T - 1) / SCAN_T;
    int lo = t * chunk; if (lo > N) lo = N;
    int hi = lo + chunk; if (hi > N) hi = N;
    int s = 0;
    for (int i = lo; i < hi; ++i) s += deg[i];
    ps[t] = s;
    __syncthreads();
    for (int off = 1; off < SCAN_T; off <<= 1) {
        int vv = (t >= off) ? ps[t - off] : 0;
        __syncthreads();
        ps[t] += vv;
        __syncthreads();
    }
    int base = (t == 0) ? 0 : ps[t - 1];
    for (int i = lo; i < hi; ++i) {
        rowstart[i] = base;
        base += deg[i];
    }
    if (t == SCAN_T - 1) rowstart[N] = E;
}

// ---- fill: pure permutation, zero atomics ----
__global__ void k_fill(const int* __restrict__ dst, const int* __restrict__ src,
                       const int* __restrict__ erank, const int* __restrict__ rowstart,
                       int* __restrict__ csr_src, int E) {
    int stride = gridDim.x * blockDim.x;
    for (int e = blockIdx.x * blockDim.x + threadIdx.x; e < E; e += stride) {
        csr_src[rowstart[dst[e]] + erank[e]] = src[e];
    }
}

// ---- aggregate: block = node, wave k = head k, lane = dim/edge-slot ----
// breadth-first: lane i computes edge i's weight (parallel exp), butterfly for
// denom, shfl-broadcast in the h-gather loop (independent 128B row loads).
__global__ void k_aggr(const int* __restrict__ rowstart, const int* __restrict__ csr_src,
                       const float* __restrict__ asrc, const float* __restrict__ adst,
                       const float* __restrict__ gmaxf,
                       const __hip_bfloat16* __restrict__ h,
                       const float* __restrict__ efeat, const float* __restrict__ x,
                       float* __restrict__ out, int N) {
    int n = blockIdx.x;
    int t = threadIdx.x, k = t >> 6, lane = t & 63;
    int beg = rowstart[n], end = rowstart[n + 1];
    float mk = gmaxf[k];
    float adk = adst[n * KH + k];
    const __hip_bfloat16* hk = h + (size_t)k * N * DIM;
    float val = 0.0f, den = 0.0f;
    for (int base = beg; base < end; base += 64) {
        int cnt = end - base; if (cnt > 64) cnt = 64;
        int sn = 0; float w = 0.0f;
        if (lane < cnt) {
            sn = csr_src[base + lane];
            float as = asrc[sn * KH + k];
            w = __expf(lrelu(adk + as) - mk);
        }
        float ws = w;
#pragma unroll
        for (int off = 32; off; off >>= 1) ws += __shfl_xor(ws, off);
        den += ws;
        for (int j = 0; j < cnt; ++j) {
            float wj = __shfl(w, j);
            int snj = __shfl(sn, j);
            val = fmaf(wj, __bfloat162float(hk[(size_t)snj * DIM + lane]), val);
        }
    }
    float coef = efeat[n * KH + k] / (den + EPSV);
    __shared__ float ls[KH][DIM];
    ls[k][lane] = val * coef;
    __syncthreads();
    if (t < DIM)
        out[(size_t)n * DIM + t] = x[(size_t)n * DIM + t] +
                                   ls[0][t] + ls[1][t] + ls[2][t] + ls[3][t];
}

extern "C" void kernel_launch(void* const* d_in, const int* in_sizes, int n_in,
                              void* d_out, int out_size, void* d_ws, size_t ws_size,
                              hipStream_t stream) {
    const float* x = (const float*)d_in[0];
    const int* adj = (const int*)d_in[1];
    const float* efeat = (const float*)d_in[2];
    const float* W = (const float*)d_in[3];
    const float* a = (const float*)d_in[4];
    float* out = (float*)d_out;

    int N = in_sizes[0] / DIM;      // 50000
    int E = in_sizes[1] / 2;        // 850000
    const int* dst = adj;
    const int* src = adj + E;

    // ws layout (all segment sizes multiples of 16 B):
    //   h bf16[KH*N*DIM] | adst f32[N*4] | asrc f32[N*4] | pmax float4[EDGE_BLKS] |
    //   gmaxf f32[4] | csr_src i32[E] | erank i32[E] | deg i32[N] |
    //   rowstart i32[N+1] | (end)
    __hip_bfloat16* h = (__hip_bfloat16*)d_ws;
    float* adst = (float*)(h + (size_t)KH * N * DIM);
    float* asrc = adst + (size_t)N * KH;
    float4* pmax = (float4*)(asrc + (size_t)N * KH);
    float* gmaxf = (float*)(pmax + EDGE_BLKS);
    int* csr_src = (int*)(gmaxf + 4);
    int* erank = csr_src + E;
    int* deg = erank + E;
    int* rowstart = deg + N;

    k_zero<<<256, 256, 0, stream>>>(deg, (size_t)N);

    k_hidden<<<HID_BLKS, 256, 0, stream>>>(x, W, a, h, adst, asrc, N);

    k_pass1<<<EDGE_BLKS, 256, 0, stream>>>(dst, src, (const float4*)adst,
                                           (const float4*)asrc, deg, erank, pmax, E);

    k_scan<<<1, SCAN_T, 0, stream>>>(pmax, gmaxf, deg, rowstart, N, E);

    k_fill<<<EDGE_BLKS, 256, 0, stream>>>(dst, src, erank, rowstart, csr_src, E);

    k_aggr<<<N, 256, 0, stream>>>(rowstart, csr_src, asrc, adst, gmaxf, h,
                                  efeat, x, out, N);
}

// Round 7
// 375.873 us; speedup vs baseline: 2.0576x; 1.2183x over previous
//
#include <hip/hip_runtime.h>
#include <hip/hip_bf16.h>

#define KH 4
#define DIM 64
#define EPSV 1e-8f
#define SCAN_T 1024
#define EDGE_BLKS 2048
#define HID_BLKS 1024

__device__ __forceinline__ float lrelu(float s) { return s > 0.0f ? s : 0.01f * s; }

// ---- zero-init (ws is poisoned 0xAA before every launch) ----
__global__ void k_zero(int* __restrict__ p, size_t n) {
    size_t i = (size_t)blockIdx.x * blockDim.x + threadIdx.x;
    size_t stride = (size_t)gridDim.x * blockDim.x;
    for (; i < n; i += stride) p[i] = 0;
}

// ---- persistent GEMV: h[n][o][k] = (x[n,:] @ W[k])[o] (bf16, head-interleaved);
//      alpha[n*4+k] = h . a ----
// W column held in 64 VGPRs per thread; block = 4 waves = 4 heads, lane = out dim.
__global__ void k_hidden(const float* __restrict__ x,
                         const float* __restrict__ W,
                         const float* __restrict__ a,
                         __hip_bfloat16* __restrict__ h,
                         float* __restrict__ adst,
                         float* __restrict__ asrc, int N) {
    int t = threadIdx.x;
    int k = t >> 6, o = t & 63;
    const float* Wk = W + k * DIM * DIM;
    float wreg[DIM];
#pragma unroll
    for (int d = 0; d < DIM; ++d) wreg[d] = Wk[d * DIM + o];  // coalesced over o
    float a_d = a[k * 2 * DIM + o];
    float a_s = a[k * 2 * DIM + DIM + o];
    __shared__ float xs[DIM];
    for (int n = blockIdx.x; n < N; n += gridDim.x) {
        __syncthreads();
        if (t < DIM) xs[t] = x[(size_t)n * DIM + t];
        __syncthreads();
        float acc = 0.0f;
#pragma unroll
        for (int d = 0; d < DIM; ++d) acc = fmaf(xs[d], wreg[d], acc);
        h[((size_t)n * DIM + o) * KH + k] = __float2bfloat16(acc);
        float pd = acc * a_d, ps = acc * a_s;
#pragma unroll
        for (int off = 32; off; off >>= 1) {
            pd += __shfl_down(pd, off);
            ps += __shfl_down(ps, off);
        }
        if (o == 0) {
            adst[n * KH + k] = pd;
            asrc[n * KH + k] = ps;
        }
    }
}

// ---- pass1: edge rank (deg histogram w/ returned rank) + per-block max partials ----
__global__ void k_pass1(const int* __restrict__ dst, const int* __restrict__ src,
                        const float4* __restrict__ adst4, const float4* __restrict__ asrc4,
                        int* __restrict__ deg, int* __restrict__ erank,
                        float4* __restrict__ pmax, int E) {
    float m0 = -1e30f, m1 = -1e30f, m2 = -1e30f, m3 = -1e30f;
    int stride = gridDim.x * blockDim.x;
    for (int e = blockIdx.x * blockDim.x + threadIdx.x; e < E; e += stride) {
        int dn = dst[e], sn = src[e];
        erank[e] = atomicAdd(&deg[dn], 1);
        float4 ad = adst4[dn], as = asrc4[sn];
        m0 = fmaxf(m0, lrelu(ad.x + as.x));
        m1 = fmaxf(m1, lrelu(ad.y + as.y));
        m2 = fmaxf(m2, lrelu(ad.z + as.z));
        m3 = fmaxf(m3, lrelu(ad.w + as.w));
    }
#pragma unroll
    for (int off = 32; off; off >>= 1) {
        m0 = fmaxf(m0, __shfl_down(m0, off));
        m1 = fmaxf(m1, __shfl_down(m1, off));
        m2 = fmaxf(m2, __shfl_down(m2, off));
        m3 = fmaxf(m3, __shfl_down(m3, off));
    }
    __shared__ float4 red[4];
    int t = threadIdx.x;
    if ((t & 63) == 0) red[t >> 6] = make_float4(m0, m1, m2, m3);
    __syncthreads();
    if (t == 0) {
        float4 r = red[0];
        for (int wv = 1; wv < 4; ++wv) {
            float4 q = red[wv];
            r.x = fmaxf(r.x, q.x); r.y = fmaxf(r.y, q.y);
            r.z = fmaxf(r.z, q.z); r.w = fmaxf(r.w, q.w);
        }
        pmax[blockIdx.x] = r;
    }
}

// ---- scan: pmax -> gmaxf[4]; deg -> rowstart (exclusive) ----
__global__ void k_scan(const float4* __restrict__ pmax, float* __restrict__ gmaxf,
                       const int* __restrict__ deg, int* __restrict__ rowstart,
                       int N, int E) {
    __shared__ float4 s4[SCAN_T];
    __shared__ int ps[SCAN_T];
    int t = threadIdx.x;
    float4 v = pmax[t], v2 = pmax[t + SCAN_T];
    v.x = fmaxf(v.x, v2.x); v.y = fmaxf(v.y, v2.y);
    v.z = fmaxf(v.z, v2.z); v.w = fmaxf(v.w, v2.w);
    s4[t] = v;
    __syncthreads();
    for (int off = SCAN_T / 2; off > 0; off >>= 1) {
        if (t < off) {
            float4 q = s4[t + off];
            s4[t].x = fmaxf(s4[t].x, q.x); s4[t].y = fmaxf(s4[t].y, q.y);
            s4[t].z = fmaxf(s4[t].z, q.z); s4[t].w = fmaxf(s4[t].w, q.w);
        }
        __syncthreads();
    }
    if (t == 0) {
        gmaxf[0] = s4[0].x; gmaxf[1] = s4[0].y;
        gmaxf[2] = s4[0].z; gmaxf[3] = s4[0].w;
    }
    // exclusive scan of deg
    int chunk = (N + SCAN_T - 1) / SCAN_T;
    int lo = t * chunk; if (lo > N) lo = N;
    int hi = lo + chunk; if (hi > N) hi = N;
    int s = 0;
    for (int i = lo; i < hi; ++i) s += deg[i];
    ps[t] = s;
    __syncthreads();
    for (int off = 1; off < SCAN_T; off <<= 1) {
        int vv = (t >= off) ? ps[t - off] : 0;
        __syncthreads();
        ps[t] += vv;
        __syncthreads();
    }
    int base = (t == 0) ? 0 : ps[t - 1];
    for (int i = lo; i < hi; ++i) {
        rowstart[i] = base;
        base += deg[i];
    }
    if (t == SCAN_T - 1) rowstart[N] = E;
}

// ---- fill: permutation + per-edge weights (dense, full lanes, zero atomics) ----
__global__ void k_fill(const int* __restrict__ dst, const int* __restrict__ src,
                       const int* __restrict__ erank, const int* __restrict__ rowstart,
                       const float4* __restrict__ adst4, const float4* __restrict__ asrc4,
                       const float* __restrict__ gmaxf,
                       int* __restrict__ csr_src, float4* __restrict__ wq, int E) {
    float mk0 = gmaxf[0], mk1 = gmaxf[1], mk2 = gmaxf[2], mk3 = gmaxf[3];
    int stride = gridDim.x * blockDim.x;
    for (int e = blockIdx.x * blockDim.x + threadIdx.x; e < E; e += stride) {
        int dn = dst[e], sn = src[e];
        int slot = rowstart[dn] + erank[e];
        csr_src[slot] = sn;
        float4 ad = adst4[dn], as = asrc4[sn];
        float4 w;
        w.x = __expf(lrelu(ad.x + as.x) - mk0);
        w.y = __expf(lrelu(ad.y + as.y) - mk1);
        w.z = __expf(lrelu(ad.z + as.z) - mk2);
        w.w = __expf(lrelu(ad.w + as.w) - mk3);
        wq[slot] = w;
    }
}

// ---- aggregate: one wave per node, all 4 heads at once; lane = dim ----
// per edge: uniform csr_src + uniform wq(16B) + coalesced 512B h-row burst;
// 4 unpack + 4 fma + 4 den-adds. No shfl, no LDS, no atomics, no syncthreads.
__global__ void k_aggr(const int* __restrict__ rowstart, const int* __restrict__ csr_src,
                       const float4* __restrict__ wq,
                       const __hip_bfloat16* __restrict__ h,
                       const float* __restrict__ efeat, const float* __restrict__ x,
                       float* __restrict__ out, int N) {
    int n = blockIdx.x * 4 + (threadIdx.x >> 6);
    if (n >= N) return;
    int o = threadIdx.x & 63;
    int beg = rowstart[n], end = rowstart[n + 1];
    const uint2* h2 = (const uint2*)h;   // h[n][o][k]: 4 bf16 = 8 B per (n,o)
    float v0 = 0.f, v1 = 0.f, v2 = 0.f, v3 = 0.f;
    float d0 = 0.f, d1 = 0.f, d2 = 0.f, d3 = 0.f;
    for (int i = beg; i < end; ++i) {
        int sn = csr_src[i];          // wave-uniform
        float4 w = wq[i];             // wave-uniform 16 B
        uint2 hv = h2[(size_t)sn * DIM + o];  // 8 B/lane, 512 B/wave burst
        float f0 = __uint_as_float(hv.x << 16);
        float f1 = __uint_as_float(hv.x & 0xFFFF0000u);
        float f2 = __uint_as_float(hv.y << 16);
        float f3 = __uint_as_float(hv.y & 0xFFFF0000u);
        v0 = fmaf(w.x, f0, v0); v1 = fmaf(w.y, f1, v1);
        v2 = fmaf(w.z, f2, v2); v3 = fmaf(w.w, f3, v3);
        d0 += w.x; d1 += w.y; d2 += w.z; d3 += w.w;
    }
    float4 ef = ((const float4*)efeat)[n];
    float c0 = ef.x / (d0 + EPSV), c1 = ef.y / (d1 + EPSV);
    float c2 = ef.z / (d2 + EPSV), c3 = ef.w / (d3 + EPSV);
    size_t oi = (size_t)n * DIM + o;
    out[oi] = x[oi] + c0 * v0 + c1 * v1 + c2 * v2 + c3 * v3;
}

extern "C" void kernel_launch(void* const* d_in, const int* in_sizes, int n_in,
                              void* d_out, int out_size, void* d_ws, size_t ws_size,
                              hipStream_t stream) {
    const float* x = (const float*)d_in[0];
    const int* adj = (const int*)d_in[1];
    const float* efeat = (const float*)d_in[2];
    const float* W = (const float*)d_in[3];
    const float* a = (const float*)d_in[4];
    float* out = (float*)d_out;

    int N = in_sizes[0] / DIM;      // 50000
    int E = in_sizes[1] / 2;        // 850000
    const int* dst = adj;
    const int* src = adj + E;

    // ws layout (all segment sizes multiples of 16 B):
    //   h bf16[N*DIM*KH] | adst f32[N*4] | asrc f32[N*4] | pmax float4[EDGE_BLKS] |
    //   gmaxf f32[4] | wq float4[E] | csr_src i32[E] | erank i32[E] |
    //   deg i32[N] | rowstart i32[N+1]
    __hip_bfloat16* h = (__hip_bfloat16*)d_ws;
    float* adst = (float*)(h + (size_t)N * DIM * KH);
    float* asrc = adst + (size_t)N * KH;
    float4* pmax = (float4*)(asrc + (size_t)N * KH);
    float* gmaxf = (float*)(pmax + EDGE_BLKS);
    float4* wq = (float4*)(gmaxf + 4);
    int* csr_src = (int*)(wq + E);
    int* erank = csr_src + E;
    int* deg = erank + E;
    int* rowstart = deg + N;

    k_zero<<<256, 256, 0, stream>>>(deg, (size_t)N);

    k_hidden<<<HID_BLKS, 256, 0, stream>>>(x, W, a, h, adst, asrc, N);

    k_pass1<<<EDGE_BLKS, 256, 0, stream>>>(dst, src, (const float4*)adst,
                                           (const float4*)asrc, deg, erank, pmax, E);

    k_scan<<<1, SCAN_T, 0, stream>>>(pmax, gmaxf, deg, rowstart, N, E);

    k_fill<<<EDGE_BLKS, 256, 0, stream>>>(dst, src, erank, rowstart,
                                          (const float4*)adst, (const float4*)asrc,
                                          gmaxf, csr_src, wq, E);

    k_aggr<<<(N + 3) / 4, 256, 0, stream>>>(rowstart, csr_src, wq, h, efeat, x, out, N);
}

// Round 8
// 341.845 us; speedup vs baseline: 2.2624x; 1.0995x over previous
//
#include <hip/hip_runtime.h>
#include <hip/hip_bf16.h>

#define KH 4
#define DIM 64
#define EPSV 1e-8f
#define SCAN_T 1024
#define EDGE_BLKS 2048
#define HID_BLKS 1024

__device__ __forceinline__ float lrelu(float s) { return s > 0.0f ? s : 0.01f * s; }
__device__ __forceinline__ float blo(unsigned u) { return __uint_as_float(u << 16); }
__device__ __forceinline__ float bhi(unsigned u) { return __uint_as_float(u & 0xFFFF0000u); }

// ---- zero-init (ws is poisoned 0xAA before every launch) ----
__global__ void k_zero(int* __restrict__ p, size_t n) {
    size_t i = (size_t)blockIdx.x * blockDim.x + threadIdx.x;
    size_t stride = (size_t)gridDim.x * blockDim.x;
    for (; i < n; i += stride) p[i] = 0;
}

// ---- persistent GEMV: h[n][o][k] = (x[n,:] @ W[k])[o] (bf16, head-interleaved);
//      alpha[n*4+k] = h . a ----
__global__ void k_hidden(const float* __restrict__ x,
                         const float* __restrict__ W,
                         const float* __restrict__ a,
                         __hip_bfloat16* __restrict__ h,
                         float* __restrict__ adst,
                         float* __restrict__ asrc, int N) {
    int t = threadIdx.x;
    int k = t >> 6, o = t & 63;
    const float* Wk = W + k * DIM * DIM;
    float wreg[DIM];
#pragma unroll
    for (int d = 0; d < DIM; ++d) wreg[d] = Wk[d * DIM + o];  // coalesced over o
    float a_d = a[k * 2 * DIM + o];
    float a_s = a[k * 2 * DIM + DIM + o];
    __shared__ float4 xs4[DIM / 4];
    for (int n = blockIdx.x; n < N; n += gridDim.x) {
        __syncthreads();
        if (t < DIM / 4) xs4[t] = ((const float4*)(x + (size_t)n * DIM))[t];
        __syncthreads();
        float acc = 0.0f;
#pragma unroll
        for (int d4 = 0; d4 < DIM / 4; ++d4) {
            float4 xv = xs4[d4];   // ds_read_b128 broadcast
            acc = fmaf(xv.x, wreg[d4 * 4 + 0], acc);
            acc = fmaf(xv.y, wreg[d4 * 4 + 1], acc);
            acc = fmaf(xv.z, wreg[d4 * 4 + 2], acc);
            acc = fmaf(xv.w, wreg[d4 * 4 + 3], acc);
        }
        h[((size_t)n * DIM + o) * KH + k] = __float2bfloat16(acc);
        float pd = acc * a_d, ps = acc * a_s;
#pragma unroll
        for (int off = 32; off; off >>= 1) {
            pd += __shfl_down(pd, off);
            ps += __shfl_down(ps, off);
        }
        if (o == 0) {
            adst[n * KH + k] = pd;
            asrc[n * KH + k] = ps;
        }
    }
}

// ---- pass1: edge rank (deg histogram w/ returned rank) + per-block max partials ----
__global__ void k_pass1(const int* __restrict__ dst, const int* __restrict__ src,
                        const float4* __restrict__ adst4, const float4* __restrict__ asrc4,
                        int* __restrict__ deg, int* __restrict__ erank,
                        float4* __restrict__ pmax, int E) {
    float m0 = -1e30f, m1 = -1e30f, m2 = -1e30f, m3 = -1e30f;
    int stride = gridDim.x * blockDim.x;
    for (int e = blockIdx.x * blockDim.x + threadIdx.x; e < E; e += stride) {
        int dn = dst[e], sn = src[e];
        erank[e] = atomicAdd(&deg[dn], 1);
        float4 ad = adst4[dn], as = asrc4[sn];
        m0 = fmaxf(m0, lrelu(ad.x + as.x));
        m1 = fmaxf(m1, lrelu(ad.y + as.y));
        m2 = fmaxf(m2, lrelu(ad.z + as.z));
        m3 = fmaxf(m3, lrelu(ad.w + as.w));
    }
#pragma unroll
    for (int off = 32; off; off >>= 1) {
        m0 = fmaxf(m0, __shfl_down(m0, off));
        m1 = fmaxf(m1, __shfl_down(m1, off));
        m2 = fmaxf(m2, __shfl_down(m2, off));
        m3 = fmaxf(m3, __shfl_down(m3, off));
    }
    __shared__ float4 red[4];
    int t = threadIdx.x;
    if ((t & 63) == 0) red[t >> 6] = make_float4(m0, m1, m2, m3);
    __syncthreads();
    if (t == 0) {
        float4 r = red[0];
        for (int wv = 1; wv < 4; ++wv) {
            float4 q = red[wv];
            r.x = fmaxf(r.x, q.x); r.y = fmaxf(r.y, q.y);
            r.z = fmaxf(r.z, q.z); r.w = fmaxf(r.w, q.w);
        }
        pmax[blockIdx.x] = r;
    }
}

// ---- scan: pmax -> gmaxf[4]; deg -> rowstart (exclusive) ----
__global__ void k_scan(const float4* __restrict__ pmax, float* __restrict__ gmaxf,
                       const int* __restrict__ deg, int* __restrict__ rowstart,
                       int N, int E) {
    __shared__ float4 s4[SCAN_T];
    __shared__ int ps[SCAN_T];
    int t = threadIdx.x;
    float4 v = pmax[t], v2 = pmax[t + SCAN_T];
    v.x = fmaxf(v.x, v2.x); v.y = fmaxf(v.y, v2.y);
    v.z = fmaxf(v.z, v2.z); v.w = fmaxf(v.w, v2.w);
    s4[t] = v;
    __syncthreads();
    for (int off = SCAN_T / 2; off > 0; off >>= 1) {
        if (t < off) {
            float4 q = s4[t + off];
            s4[t].x = fmaxf(s4[t].x, q.x); s4[t].y = fmaxf(s4[t].y, q.y);
            s4[t].z = fmaxf(s4[t].z, q.z); s4[t].w = fmaxf(s4[t].w, q.w);
        }
        __syncthreads();
    }
    if (t == 0) {
        gmaxf[0] = s4[0].x; gmaxf[1] = s4[0].y;
        gmaxf[2] = s4[0].z; gmaxf[3] = s4[0].w;
    }
    // exclusive scan of deg
    int chunk = (N + SCAN_T - 1) / SCAN_T;
    int lo = t * chunk; if (lo > N) lo = N;
    int hi = lo + chunk; if (hi > N) hi = N;
    int s = 0;
    for (int i = lo; i < hi; ++i) s += deg[i];
    ps[t] = s;
    __syncthreads();
    for (int off = 1; off < SCAN_T; off <<= 1) {
        int vv = (t >= off) ? ps[t - off] : 0;
        __syncthreads();
        ps[t] += vv;
        __syncthreads();
    }
    int base = (t == 0) ? 0 : ps[t - 1];
    for (int i = lo; i < hi; ++i) {
        rowstart[i] = base;
        base += deg[i];
    }
    if (t == SCAN_T - 1) rowstart[N] = E;
}

// ---- fill: permutation + per-edge weights (dense, full lanes, zero atomics) ----
__global__ void k_fill(const int* __restrict__ dst, const int* __restrict__ src,
                       const int* __restrict__ erank, const int* __restrict__ rowstart,
                       const float4* __restrict__ adst4, const float4* __restrict__ asrc4,
                       const float* __restrict__ gmaxf,
                       int* __restrict__ csr_src, float4* __restrict__ wq, int E) {
    float mk0 = gmaxf[0], mk1 = gmaxf[1], mk2 = gmaxf[2], mk3 = gmaxf[3];
    int stride = gridDim.x * blockDim.x;
    for (int e = blockIdx.x * blockDim.x + threadIdx.x; e < E; e += stride) {
        int dn = dst[e], sn = src[e];
        int slot = rowstart[dn] + erank[e];
        csr_src[slot] = sn;
        float4 ad = adst4[dn], as = asrc4[sn];
        float4 w;
        w.x = __expf(lrelu(ad.x + as.x) - mk0);
        w.y = __expf(lrelu(ad.y + as.y) - mk1);
        w.z = __expf(lrelu(ad.z + as.z) - mk2);
        w.w = __expf(lrelu(ad.w + as.w) - mk3);
        wq[slot] = w;
    }
}

// ---- aggregate: one wave per node, all 4 heads; lane = dim; 4x unrolled ----
// per chunk: 4 csr + 4 wq loads (independent), then 4 independent 512B h-row
// gathers, then 48 VALU. No shfl/LDS/atomics/syncthreads.
__global__ void k_aggr(const int* __restrict__ rowstart, const int* __restrict__ csr_src,
                       const float4* __restrict__ wq,
                       const __hip_bfloat16* __restrict__ h,
                       const float* __restrict__ efeat, const float* __restrict__ x,
                       float* __restrict__ out, int N) {
    int n = blockIdx.x * 4 + (threadIdx.x >> 6);
    if (n >= N) return;
    int o = threadIdx.x & 63;
    int beg = rowstart[n], end = rowstart[n + 1];
    const uint2* h2 = (const uint2*)h;   // h[n][o][k]: 4 bf16 = 8 B per (n,o)
    float v0 = 0.f, v1 = 0.f, v2 = 0.f, v3 = 0.f;
    float d0 = 0.f, d1 = 0.f, d2 = 0.f, d3 = 0.f;
    int i = beg;
    for (; i + 4 <= end; i += 4) {
        int s0 = csr_src[i + 0], s1 = csr_src[i + 1];
        int s2 = csr_src[i + 2], s3 = csr_src[i + 3];
        float4 w0 = wq[i + 0], w1 = wq[i + 1], w2 = wq[i + 2], w3 = wq[i + 3];
        uint2 a0 = h2[(size_t)s0 * DIM + o];
        uint2 a1 = h2[(size_t)s1 * DIM + o];
        uint2 a2 = h2[(size_t)s2 * DIM + o];
        uint2 a3 = h2[(size_t)s3 * DIM + o];
        v0 = fmaf(w0.x, blo(a0.x), v0); v1 = fmaf(w0.y, bhi(a0.x), v1);
        v2 = fmaf(w0.z, blo(a0.y), v2); v3 = fmaf(w0.w, bhi(a0.y), v3);
        d0 += w0.x; d1 += w0.y; d2 += w0.z; d3 += w0.w;
        v0 = fmaf(w1.x, blo(a1.x), v0); v1 = fmaf(w1.y, bhi(a1.x), v1);
        v2 = fmaf(w1.z, blo(a1.y), v2); v3 = fmaf(w1.w, bhi(a1.y), v3);
        d0 += w1.x; d1 += w1.y; d2 += w1.z; d3 += w1.w;
        v0 = fmaf(w2.x, blo(a2.x), v0); v1 = fmaf(w2.y, bhi(a2.x), v1);
        v2 = fmaf(w2.z, blo(a2.y), v2); v3 = fmaf(w2.w, bhi(a2.y), v3);
        d0 += w2.x; d1 += w2.y; d2 += w2.z; d3 += w2.w;
        v0 = fmaf(w3.x, blo(a3.x), v0); v1 = fmaf(w3.y, bhi(a3.x), v1);
        v2 = fmaf(w3.z, blo(a3.y), v2); v3 = fmaf(w3.w, bhi(a3.y), v3);
        d0 += w3.x; d1 += w3.y; d2 += w3.z; d3 += w3.w;
    }
    for (; i < end; ++i) {
        int sn = csr_src[i];
        float4 w = wq[i];
        uint2 hv = h2[(size_t)sn * DIM + o];
        v0 = fmaf(w.x, blo(hv.x), v0); v1 = fmaf(w.y, bhi(hv.x), v1);
        v2 = fmaf(w.z, blo(hv.y), v2); v3 = fmaf(w.w, bhi(hv.y), v3);
        d0 += w.x; d1 += w.y; d2 += w.z; d3 += w.w;
    }
    float4 ef = ((const float4*)efeat)[n];
    float c0 = ef.x / (d0 + EPSV), c1 = ef.y / (d1 + EPSV);
    float c2 = ef.z / (d2 + EPSV), c3 = ef.w / (d3 + EPSV);
    size_t oi = (size_t)n * DIM + o;
    out[oi] = x[oi] + c0 * v0 + c1 * v1 + c2 * v2 + c3 * v3;
}

extern "C" void kernel_launch(void* const* d_in, const int* in_sizes, int n_in,
                              void* d_out, int out_size, void* d_ws, size_t ws_size,
                              hipStream_t stream) {
    const float* x = (const float*)d_in[0];
    const int* adj = (const int*)d_in[1];
    const float* efeat = (const float*)d_in[2];
    const float* W = (const float*)d_in[3];
    const float* a = (const float*)d_in[4];
    float* out = (float*)d_out;

    int N = in_sizes[0] / DIM;      // 50000
    int E = in_sizes[1] / 2;        // 850000
    const int* dst = adj;
    const int* src = adj + E;

    // ws layout (all segment sizes multiples of 16 B):
    //   h bf16[N*DIM*KH] | adst f32[N*4] | asrc f32[N*4] | pmax float4[EDGE_BLKS] |
    //   gmaxf f32[4] | wq float4[E] | csr_src i32[E] | erank i32[E] |
    //   deg i32[N] | rowstart i32[N+1]
    __hip_bfloat16* h = (__hip_bfloat16*)d_ws;
    float* adst = (float*)(h + (size_t)N * DIM * KH);
    float* asrc = adst + (size_t)N * KH;
    float4* pmax = (float4*)(asrc + (size_t)N * KH);
    float* gmaxf = (float*)(pmax + EDGE_BLKS);
    float4* wq = (float4*)(gmaxf + 4);
    int* csr_src = (int*)(wq + E);
    int* erank = csr_src + E;
    int* deg = erank + E;
    int* rowstart = deg + N;

    k_zero<<<256, 256, 0, stream>>>(deg, (size_t)N);

    k_hidden<<<HID_BLKS, 256, 0, stream>>>(x, W, a, h, adst, asrc, N);

    k_pass1<<<EDGE_BLKS, 256, 0, stream>>>(dst, src, (const float4*)adst,
                                           (const float4*)asrc, deg, erank, pmax, E);

    k_scan<<<1, SCAN_T, 0, stream>>>(pmax, gmaxf, deg, rowstart, N, E);

    k_fill<<<EDGE_BLKS, 256, 0, stream>>>(dst, src, erank, rowstart,
                                          (const float4*)adst, (const float4*)asrc,
                                          gmaxf, csr_src, wq, E);

    k_aggr<<<(N + 3) / 4, 256, 0, stream>>>(rowstart, csr_src, wq, h, efeat, x, out, N);
}

// Round 9
// 277.087 us; speedup vs baseline: 2.7911x; 1.2337x over previous
//
#include <hip/hip_runtime.h>
#include <hip/hip_bf16.h>

#define KH 4
#define DIM 64
#define EPSV 1e-8f
#define EDGE_BLKS 2048
#define HID_BLKS 1024
#define SCAN_CHUNK 512

__device__ __forceinline__ float lrelu(float s) { return s > 0.0f ? s : 0.01f * s; }
__device__ __forceinline__ float blo(unsigned u) { return __uint_as_float(u << 16); }
__device__ __forceinline__ float bhi(unsigned u) { return __uint_as_float(u & 0xFFFF0000u); }

// ---- zero-init (ws is poisoned 0xAA before every launch) ----
__global__ void k_zero(int* __restrict__ p, size_t n) {
    size_t i = (size_t)blockIdx.x * blockDim.x + threadIdx.x;
    size_t stride = (size_t)gridDim.x * blockDim.x;
    for (; i < n; i += stride) p[i] = 0;
}

// ---- persistent GEMV: h[n][o][k] (bf16 interleaved); alpha[n*4+k]; block-max of alphas ----
__global__ void k_hidden(const float* __restrict__ x,
                         const float* __restrict__ W,
                         const float* __restrict__ a,
                         __hip_bfloat16* __restrict__ h,
                         float* __restrict__ adst,
                         float* __restrict__ asrc,
                         float* __restrict__ pmaxd,
                         float* __restrict__ pmaxs, int N) {
    int t = threadIdx.x;
    int k = t >> 6, o = t & 63;
    const float* Wk = W + k * DIM * DIM;
    float wreg[DIM];
#pragma unroll
    for (int d = 0; d < DIM; ++d) wreg[d] = Wk[d * DIM + o];  // coalesced over o
    float a_d = a[k * 2 * DIM + o];
    float a_s = a[k * 2 * DIM + DIM + o];
    float mpd = -1e30f, mps = -1e30f;
    __shared__ float4 xs4[DIM / 4];
    for (int n = blockIdx.x; n < N; n += gridDim.x) {
        __syncthreads();
        if (t < DIM / 4) xs4[t] = ((const float4*)(x + (size_t)n * DIM))[t];
        __syncthreads();
        float acc = 0.0f;
#pragma unroll
        for (int d4 = 0; d4 < DIM / 4; ++d4) {
            float4 xv = xs4[d4];   // ds_read_b128 broadcast
            acc = fmaf(xv.x, wreg[d4 * 4 + 0], acc);
            acc = fmaf(xv.y, wreg[d4 * 4 + 1], acc);
            acc = fmaf(xv.z, wreg[d4 * 4 + 2], acc);
            acc = fmaf(xv.w, wreg[d4 * 4 + 3], acc);
        }
        h[((size_t)n * DIM + o) * KH + k] = __float2bfloat16(acc);
        float pd = acc * a_d, ps = acc * a_s;
#pragma unroll
        for (int off = 32; off; off >>= 1) {
            pd += __shfl_down(pd, off);
            ps += __shfl_down(ps, off);
        }
        if (o == 0) {
            adst[n * KH + k] = pd;
            asrc[n * KH + k] = ps;
            mpd = fmaxf(mpd, pd);
            mps = fmaxf(mps, ps);
        }
    }
    if (o == 0) {
        pmaxd[blockIdx.x * KH + k] = mpd;
        pmaxs[blockIdx.x * KH + k] = mps;
    }
}

// ---- rank: erank[e] = arrival rank at dst; deg histogram ----
__global__ void k_rank(const int* __restrict__ dst, int* __restrict__ deg,
                       int* __restrict__ erank, int E) {
    int stride = gridDim.x * blockDim.x;
    for (int e = blockIdx.x * blockDim.x + threadIdx.x; e < E; e += stride)
        erank[e] = atomicAdd(&deg[dst[e]], 1);
}

// ---- scan1: block-local exclusive scan of deg (512/block) -> rowstart, bsum ----
__global__ void k_scan1(const int* __restrict__ deg, int* __restrict__ rowstart,
                        int* __restrict__ bsum, int N) {
    __shared__ int ps[256];
    int b = blockIdx.x, t = threadIdx.x;
    int i0 = b * SCAN_CHUNK + 2 * t;
    int d0 = (i0 < N) ? deg[i0] : 0;
    int d1 = (i0 + 1 < N) ? deg[i0 + 1] : 0;
    ps[t] = d0 + d1;
    __syncthreads();
    for (int off = 1; off < 256; off <<= 1) {
        int v = (t >= off) ? ps[t - off] : 0;
        __syncthreads();
        ps[t] += v;
        __syncthreads();
    }
    int excl = (t == 0) ? 0 : ps[t - 1];
    if (i0 < N) rowstart[i0] = excl;
    if (i0 + 1 < N) rowstart[i0 + 1] = excl + d0;
    if (t == 255) bsum[b] = ps[255];
}

// ---- scan2: scan bsum -> bbase; reduce alpha-max partials -> gmaxf ----
__global__ void k_scan2(const float* __restrict__ pmaxd, const float* __restrict__ pmaxs,
                        float* __restrict__ gmaxf,
                        const int* __restrict__ bsum, int* __restrict__ bbase, int nb) {
    __shared__ float rd[256], rs[256];
    __shared__ int sb[256];
    int t = threadIdx.x;
    float md = -1e30f, ms = -1e30f;
    for (int i = t; i < HID_BLKS * KH; i += 256) {   // stride 256 preserves i&3
        md = fmaxf(md, pmaxd[i]);
        ms = fmaxf(ms, pmaxs[i]);
    }
    rd[t] = md; rs[t] = ms;
    __syncthreads();
    for (int off = 128; off >= 4; off >>= 1) {
        if (t < off) {
            rd[t] = fmaxf(rd[t], rd[t + off]);
            rs[t] = fmaxf(rs[t], rs[t + off]);
        }
        __syncthreads();
    }
    if (t < KH) gmaxf[t] = lrelu(rd[t] + rs[t]);   // upper bound of all head-t logits
    if (t < nb) sb[t] = bsum[t];
    __syncthreads();
    if (t == 0) {
        int run = 0;
        for (int i = 0; i < nb; ++i) { int v = sb[i]; sb[i] = run; run += v; }
    }
    __syncthreads();
    if (t < nb) bbase[t] = sb[t];
}

// ---- scan3: rowstart[i] += bbase[block]; rowstart[N] = E ----
__global__ void k_scan3(int* __restrict__ rowstart, const int* __restrict__ bbase,
                        int N, int E) {
    int b = blockIdx.x, t = threadIdx.x;
    int base = bbase[b];
    int i0 = b * SCAN_CHUNK + 2 * t;
    if (i0 < N) rowstart[i0] += base;
    if (i0 + 1 < N) rowstart[i0 + 1] += base;
    if (b == 0 && t == 0) rowstart[N] = E;
}

// ---- fill: permutation + per-edge weights (dense, full lanes, zero atomics) ----
__global__ void k_fill(const int* __restrict__ dst, const int* __restrict__ src,
                       const int* __restrict__ erank, const int* __restrict__ rowstart,
                       const float4* __restrict__ adst4, const float4* __restrict__ asrc4,
                       const float* __restrict__ gmaxf,
                       int* __restrict__ csr_src, float4* __restrict__ wq, int E) {
    float mk0 = gmaxf[0], mk1 = gmaxf[1], mk2 = gmaxf[2], mk3 = gmaxf[3];
    int stride = gridDim.x * blockDim.x;
    for (int e = blockIdx.x * blockDim.x + threadIdx.x; e < E; e += stride) {
        int dn = dst[e], sn = src[e];
        int slot = rowstart[dn] + erank[e];
        csr_src[slot] = sn;
        float4 ad = adst4[dn], as = asrc4[sn];
        float4 w;
        w.x = __expf(lrelu(ad.x + as.x) - mk0);
        w.y = __expf(lrelu(ad.y + as.y) - mk1);
        w.z = __expf(lrelu(ad.z + as.z) - mk2);
        w.w = __expf(lrelu(ad.w + as.w) - mk3);
        wq[slot] = w;
    }
}

// ---- aggregate: one wave per node, all 4 heads; lane = dim; 4x unrolled ----
__global__ void k_aggr(const int* __restrict__ rowstart, const int* __restrict__ csr_src,
                       const float4* __restrict__ wq,
                       const __hip_bfloat16* __restrict__ h,
                       const float* __restrict__ efeat, const float* __restrict__ x,
                       float* __restrict__ out, int N) {
    int n = blockIdx.x * 4 + (threadIdx.x >> 6);
    if (n >= N) return;
    int o = threadIdx.x & 63;
    int beg = rowstart[n], end = rowstart[n + 1];
    const uint2* h2 = (const uint2*)h;   // h[n][o][k]: 4 bf16 = 8 B per (n,o)
    float v0 = 0.f, v1 = 0.f, v2 = 0.f, v3 = 0.f;
    float d0 = 0.f, d1 = 0.f, d2 = 0.f, d3 = 0.f;
    int i = beg;
    for (; i + 4 <= end; i += 4) {
        int s0 = csr_src[i + 0], s1 = csr_src[i + 1];
        int s2 = csr_src[i + 2], s3 = csr_src[i + 3];
        float4 w0 = wq[i + 0], w1 = wq[i + 1], w2 = wq[i + 2], w3 = wq[i + 3];
        uint2 a0 = h2[(size_t)s0 * DIM + o];
        uint2 a1 = h2[(size_t)s1 * DIM + o];
        uint2 a2 = h2[(size_t)s2 * DIM + o];
        uint2 a3 = h2[(size_t)s3 * DIM + o];
        v0 = fmaf(w0.x, blo(a0.x), v0); v1 = fmaf(w0.y, bhi(a0.x), v1);
        v2 = fmaf(w0.z, blo(a0.y), v2); v3 = fmaf(w0.w, bhi(a0.y), v3);
        d0 += w0.x; d1 += w0.y; d2 += w0.z; d3 += w0.w;
        v0 = fmaf(w1.x, blo(a1.x), v0); v1 = fmaf(w1.y, bhi(a1.x), v1);
        v2 = fmaf(w1.z, blo(a1.y), v2); v3 = fmaf(w1.w, bhi(a1.y), v3);
        d0 += w1.x; d1 += w1.y; d2 += w1.z; d3 += w1.w;
        v0 = fmaf(w2.x, blo(a2.x), v0); v1 = fmaf(w2.y, bhi(a2.x), v1);
        v2 = fmaf(w2.z, blo(a2.y), v2); v3 = fmaf(w2.w, bhi(a2.y), v3);
        d0 += w2.x; d1 += w2.y; d2 += w2.z; d3 += w2.w;
        v0 = fmaf(w3.x, blo(a3.x), v0); v1 = fmaf(w3.y, bhi(a3.x), v1);
        v2 = fmaf(w3.z, blo(a3.y), v2); v3 = fmaf(w3.w, bhi(a3.y), v3);
        d0 += w3.x; d1 += w3.y; d2 += w3.z; d3 += w3.w;
    }
    for (; i < end; ++i) {
        int sn = csr_src[i];
        float4 w = wq[i];
        uint2 hv = h2[(size_t)sn * DIM + o];
        v0 = fmaf(w.x, blo(hv.x), v0); v1 = fmaf(w.y, bhi(hv.x), v1);
        v2 = fmaf(w.z, blo(hv.y), v2); v3 = fmaf(w.w, bhi(hv.y), v3);
        d0 += w.x; d1 += w.y; d2 += w.z; d3 += w.w;
    }
    float4 ef = ((const float4*)efeat)[n];
    float c0 = ef.x / (d0 + EPSV), c1 = ef.y / (d1 + EPSV);
    float c2 = ef.z / (d2 + EPSV), c3 = ef.w / (d3 + EPSV);
    size_t oi = (size_t)n * DIM + o;
    out[oi] = x[oi] + c0 * v0 + c1 * v1 + c2 * v2 + c3 * v3;
}

extern "C" void kernel_launch(void* const* d_in, const int* in_sizes, int n_in,
                              void* d_out, int out_size, void* d_ws, size_t ws_size,
                              hipStream_t stream) {
    const float* x = (const float*)d_in[0];
    const int* adj = (const int*)d_in[1];
    const float* efeat = (const float*)d_in[2];
    const float* W = (const float*)d_in[3];
    const float* a = (const float*)d_in[4];
    float* out = (float*)d_out;

    int N = in_sizes[0] / DIM;      // 50000
    int E = in_sizes[1] / 2;        // 850000
    const int* dst = adj;
    const int* src = adj + E;
    int nscan = (N + SCAN_CHUNK - 1) / SCAN_CHUNK;   // 98

    // ws layout (every segment's byte size is a multiple of 16):
    //   h bf16[N*DIM*KH] | adst f32[N*4] | asrc f32[N*4] |
    //   pmaxd f32[HID_BLKS*KH] | pmaxs f32[HID_BLKS*KH] | gmaxf f32[4] |
    //   bsum i32[128] | bbase i32[128] | wq float4[E] | csr_src i32[E] |
    //   erank i32[E] | deg i32[N] | rowstart i32[N+1]
    __hip_bfloat16* h = (__hip_bfloat16*)d_ws;
    float* adst = (float*)(h + (size_t)N * DIM * KH);
    float* asrc = adst + (size_t)N * KH;
    float* pmaxd = asrc + (size_t)N * KH;
    float* pmaxs = pmaxd + HID_BLKS * KH;
    float* gmaxf = pmaxs + HID_BLKS * KH;
    int* bsum = (int*)(gmaxf + 4);
    int* bbase = bsum + 128;
    float4* wq = (float4*)(bbase + 128);
    int* csr_src = (int*)(wq + E);
    int* erank = csr_src + E;
    int* deg = erank + E;
    int* rowstart = deg + N;

    k_zero<<<256, 256, 0, stream>>>(deg, (size_t)N);

    k_hidden<<<HID_BLKS, 256, 0, stream>>>(x, W, a, h, adst, asrc, pmaxd, pmaxs, N);

    k_rank<<<EDGE_BLKS, 256, 0, stream>>>(dst, deg, erank, E);

    k_scan1<<<nscan, 256, 0, stream>>>(deg, rowstart, bsum, N);

    k_scan2<<<1, 256, 0, stream>>>(pmaxd, pmaxs, gmaxf, bsum, bbase, nscan);

    k_scan3<<<nscan, 256, 0, stream>>>(rowstart, bbase, N, E);

    k_fill<<<EDGE_BLKS, 256, 0, stream>>>(dst, src, erank, rowstart,
                                          (const float4*)adst, (const float4*)asrc,
                                          gmaxf, csr_src, wq, E);

    k_aggr<<<(N + 3) / 4, 256, 0, stream>>>(rowstart, csr_src, wq, h, efeat, x, out, N);
}